// Round 5
// baseline (243.312 us; speedup 1.0000x reference)
//
#include <hip/hip_runtime.h>
#include <math.h>

// BatchHardTripletMarginLoss on MI355X — round 5: pipelined swizzled mine.
// Pipeline (all on `stream`, graph-capture safe):
//   memset  : zero flagbits (hipMemsetAsync — capture-legal)
//   detect  : sniff positives_mask storage format via evidence bits
//   repack  : positives_mask -> packed bitmask via __ballot, 4 words/thread batched
//   convert : E fp32 -> fp16 (for MFMA) + sq[i] = ||E_i||^2 in fp32
//   mine    : fp16 MFMA Gram, BK=64, reg-prefetch pipeline, XOR-swizzled LDS
//   finalize: fused combine (32-chunk argmax/argmin) + fp32 distance recompute -> loss[a]
//   reduce  : single-block tree-reduce of loss[] -> out = cnt>0 ? sum/cnt : 0
// Accuracy: fp16 only affects WHICH indices are mined (d2 err ~0.02 vs rival
// gaps ~13); the loss values are recomputed in fp32.

#define NN 4096
#define DD 256
#define MARGIN 0.2f
#define NCHUNK 32            // one 128-col j-tile per chunk
#define BK 64                // K-chunk in halves (2 MFMA substeps)

typedef _Float16 f16;
typedef __attribute__((ext_vector_type(8))) _Float16 f16x8;
typedef __attribute__((ext_vector_type(4))) _Float16 f16x4;
typedef __attribute__((ext_vector_type(4))) float f32x4;
typedef unsigned long long u64;

// ws byte offsets
#define OFF_FLAG   0         // evidence bitfield: 1=u8, 2=f32, 4=f64, 8=odd-dword(int32)
#define OFF_SQ     64                                    // 16 KB
#define OFF_EH     (OFF_SQ + NN * 4)                     // 2 MB fp16 embeddings
#define OFF_POSB   (OFF_EH + NN * DD * 2)                // 2 MB packed positives
#define OFF_PPV    (OFF_POSB + (NN * (long)NN / 8))      // 512 KB each partial
#define OFF_PPI    (OFF_PPV + NN * NCHUNK * 4)
#define OFF_PNV    (OFF_PPI + NN * NCHUNK * 4)
#define OFF_PNI    (OFF_PNV + NN * NCHUNK * 4)
#define OFF_LOSS   (OFF_PNI + NN * NCHUNK * 4)           // 16 KB per-anchor losses

// ---------------------------------------------------------------------------
// Mask format sniffer over the first 256 KB of positives_mask (~1.5% ones →
// still hundreds of true entries in-window under every candidate encoding).
__global__ void detect_kernel(const unsigned int* __restrict__ pos_dw,
                              int* __restrict__ flagbits) {
  int ev = 0;
  const int stride = gridDim.x * blockDim.x;
  for (int di = blockIdx.x * blockDim.x + threadIdx.x; di < 65536; di += stride) {
    const unsigned int v = pos_dw[di];
    if (v & 0xffffff00u) ev |= 1;                     // bytes beyond an int32 0/1 bool
    if (v == 0x3f800000u) ev |= 2;                    // 1.0f dword
    if (v == 0x3ff00000u && (di & 1)) ev |= 4;        // high dword of 1.0 double
    if (v && (di & 1)) ev |= 8;                       // int32 bools populate odd dwords
  }
  for (int off = 32; off > 0; off >>= 1) ev |= __shfl_down(ev, off);
  if ((threadIdx.x & 63) == 0 && ev) atomicOr(flagbits, ev);
}

__device__ __forceinline__ int decode_flag(int fb) {
  if (fb & 2) return 2;        // float32
  if (fb & 4) return 4;        // float64
  if (fb & 1) return 1;        // uint8
  if (fb & 8) return 0;        // int32
  return 3;                    // int64
}

// ---------------------------------------------------------------------------
// Ballot repack of positives only, 4 words per thread (batched loads for MLP).
// Wave=64: one __ballot is exactly one packed output word. neg derived later.
__global__ __launch_bounds__(256)
void repack_kernel(const void* __restrict__ pos_raw,
                   u64* __restrict__ posb,
                   const int* __restrict__ flagbits) {
  const long long stride = (long long)gridDim.x * blockDim.x;
  const long long base = (long long)blockIdx.x * blockDim.x + threadIdx.x;
  const int f = decode_flag(*flagbits);
  bool pr[4];
  if (f == 0) {
    const unsigned int* s = (const unsigned int*)pos_raw;
#pragma unroll
    for (int it = 0; it < 4; ++it) pr[it] = s[base + it * stride] != 0u;
  } else if (f == 1) {
    const unsigned char* s = (const unsigned char*)pos_raw;
#pragma unroll
    for (int it = 0; it < 4; ++it) pr[it] = s[base + it * stride] != 0;
  } else if (f == 2) {
    const float* s = (const float*)pos_raw;
#pragma unroll
    for (int it = 0; it < 4; ++it) pr[it] = s[base + it * stride] != 0.f;
  } else if (f == 3) {
    const u64* s = (const u64*)pos_raw;
#pragma unroll
    for (int it = 0; it < 4; ++it) pr[it] = s[base + it * stride] != 0ull;
  } else {
    const double* s = (const double*)pos_raw;
#pragma unroll
    for (int it = 0; it < 4; ++it) pr[it] = s[base + it * stride] != 0.0;
  }
#pragma unroll
  for (int it = 0; it < 4; ++it) {
    const u64 w = __ballot(pr[it]);
    if ((threadIdx.x & 63) == 0) posb[(base + it * stride) >> 6] = w;
  }
}

// ---------------------------------------------------------------------------
// E fp32 -> fp16 + squared norms. One wave per row.
__global__ __launch_bounds__(256)
void convert_kernel(const float* __restrict__ E, f16* __restrict__ Eh,
                    float* __restrict__ sq) {
  const int row = blockIdx.x * 4 + (threadIdx.x >> 6);
  const int lane = threadIdx.x & 63;
  const float4 v = *(const float4*)&E[(size_t)row * DD + lane * 4];
  f16x4 h;
  h[0] = (f16)v.x; h[1] = (f16)v.y; h[2] = (f16)v.z; h[3] = (f16)v.w;
  *(f16x4*)&Eh[(size_t)row * DD + lane * 4] = h;
  float s = v.x * v.x + v.y * v.y + v.z * v.z + v.w * v.w;
#pragma unroll
  for (int off = 32; off > 0; off >>= 1) s += __shfl_down(s, off);
  if (lane == 0) sq[row] = s;
}

// ---------------------------------------------------------------------------
// XOR swizzle: row stride 64 halves (128 B = all 32 banks); 16-B granule g of
// row r stored at position g ^ s(r), s(r) = (r ^ r>>3) & 7. Analysis: every
// ds_write_b128 / ds_read_b128 in this kernel touches each bank-group exactly
// 8x across the 64 lanes -> minimum phases, zero conflicts.
__device__ __forceinline__ int swz(int r) { return (r ^ (r >> 3)) & 7; }

// MFMA Gram + batch-hard mining. 128x128 tile per block; 4 waves in a 2x2
// grid, each wave a 4x4 grid of 16x16x32_f16 MFMAs. BK=64 (2 substeps/chunk,
// 4 chunks): half the barriers of BK=32. Register prefetch: chunk k+1's
// global loads are issued right after the barrier, in flight during chunk k's
// ds_reads + 32 MFMAs. Epilogue: per-row masked max/min with index,
// quad-butterfly + LDS cross-wave reduce.
__global__ __launch_bounds__(256)
void mine_kernel(const f16* __restrict__ Eh, const float* __restrict__ sq,
                 const u64* __restrict__ posb,
                 float* __restrict__ part_pv, int* __restrict__ part_pi,
                 float* __restrict__ part_nv, int* __restrict__ part_ni) {
  __shared__ union {
    struct { f16 A[128 * BK]; f16 B[128 * BK]; } t;                   // 32 KB
    struct { float pv[2][128]; int pi[2][128];
             float nv[2][128]; int ni[2][128]; } r;                   // 4 KB
  } sm;

  const int tid = threadIdx.x;
  const int lane = tid & 63, wave = tid >> 6;
  const int lx = lane & 15, q = lane >> 4;
  const int wr = wave >> 1, wc = wave & 1;
  const int ib = blockIdx.x & 31, jb = blockIdx.x >> 5;
  const int i0 = ib * 128, j0 = jb * 128;

  f32x4 acc[4][4];
#pragma unroll
  for (int mt = 0; mt < 4; ++mt)
#pragma unroll
    for (int nt = 0; nt < 4; ++nt) acc[mt][nt] = (f32x4)0.f;

  // staging: thread t owns row t>>1, granules (t&1)*4 .. +3 (64 B of A, 64 B of B)
  const int srow = tid >> 1;
  const int scg = (tid & 1) * 4;
  const int ssw = swz(srow);
  const size_t arow = (size_t)(i0 + srow) * DD + scg * 8;
  const size_t brow = (size_t)(j0 + srow) * DD + scg * 8;

  float4 ra[4], rb[4];
#pragma unroll
  for (int u = 0; u < 4; ++u) {            // prefetch chunk 0
    ra[u] = *(const float4*)(Eh + arow + u * 8);
    rb[u] = *(const float4*)(Eh + brow + u * 8);
  }

  for (int kk = 0; kk < DD; kk += BK) {
    __syncthreads();                        // LDS free (prev chunk's reads done)
#pragma unroll
    for (int u = 0; u < 4; ++u) {
      const int p = ((scg + u) ^ ssw) << 3; // granule -> half offset
      *(float4*)&sm.t.A[srow * BK + p] = ra[u];
      *(float4*)&sm.t.B[srow * BK + p] = rb[u];
    }
    __syncthreads();
    if (kk + BK < DD) {                     // issue next chunk's loads now
#pragma unroll
      for (int u = 0; u < 4; ++u) {
        ra[u] = *(const float4*)(Eh + arow + (kk + BK) + u * 8);
        rb[u] = *(const float4*)(Eh + brow + (kk + BK) + u * 8);
      }
    }
#pragma unroll
    for (int ss = 0; ss < 2; ++ss) {
      f16x8 af[4], bf[4];
#pragma unroll
      for (int mt = 0; mt < 4; ++mt) {
        const int r = wr * 64 + mt * 16 + lx;
        af[mt] = *(const f16x8*)&sm.t.A[r * BK + (((ss * 4 + q) ^ swz(r)) << 3)];
      }
#pragma unroll
      for (int nt = 0; nt < 4; ++nt) {
        const int r = wc * 64 + nt * 16 + lx;
        bf[nt] = *(const f16x8*)&sm.t.B[r * BK + (((ss * 4 + q) ^ swz(r)) << 3)];
      }
#pragma unroll
      for (int mt = 0; mt < 4; ++mt)
#pragma unroll
        for (int nt = 0; nt < 4; ++nt)
          acc[mt][nt] = __builtin_amdgcn_mfma_f32_16x16x32_f16(af[mt], bf[nt], acc[mt][nt], 0, 0, 0);
    }
  }

  // ------- epilogue: d2 + masked mining -------
  float sqj[4];
#pragma unroll
  for (int nt = 0; nt < 4; ++nt) sqj[nt] = sq[j0 + wc * 64 + nt * 16 + lx];
  const int jw = (j0 + wc * 64) >> 6;  // mask word index for this wave's 64 cols

  __syncthreads();  // all frag reads done; LDS becomes the mining buffer

#pragma unroll
  for (int mt = 0; mt < 4; ++mt) {
#pragma unroll
    for (int r = 0; r < 4; ++r) {
      const int lr = wr * 64 + mt * 16 + q * 4 + r;   // local row 0..127
      const int gi = i0 + lr;
      const float sqi = sq[gi];
      const u64 pw = posb[(size_t)gi * (NN / 64) + jw];
      const u64 nw = ~(pw | (((gi >> 6) == jw) ? (1ull << (gi & 63)) : 0ull));
      float pb = -1e30f, nb = 1e30f;
      int pi_ = 1 << 30, ni_ = 1 << 30;
#pragma unroll
      for (int nt = 0; nt < 4; ++nt) {
        const int c = nt * 16 + lx;                    // col within the 64-word
        const int gj = j0 + wc * 64 + c;
        const float d2 = fmaxf(fmaf(-2.f, acc[mt][nt][r], sqi + sqj[nt]), 0.f);
        if ((pw >> c) & 1ull) { if (d2 > pb) { pb = d2; pi_ = gj; } }
        if ((nw >> c) & 1ull) { if (d2 < nb) { nb = d2; ni_ = gj; } }
      }
      // butterfly across the 16 lanes of this quad (offsets < 16 stay in-quad)
#pragma unroll
      for (int off = 1; off < 16; off <<= 1) {
        float ov = __shfl_xor(pb, off); int oi = __shfl_xor(pi_, off);
        if (ov > pb || (ov == pb && oi < pi_)) { pb = ov; pi_ = oi; }
        ov = __shfl_xor(nb, off); oi = __shfl_xor(ni_, off);
        if (ov < nb || (ov == nb && oi < ni_)) { nb = ov; ni_ = oi; }
      }
      if (lx == 0) {
        sm.r.pv[wc][lr] = pb; sm.r.pi[wc][lr] = pi_;
        sm.r.nv[wc][lr] = nb; sm.r.ni[wc][lr] = ni_;
      }
    }
  }

  __syncthreads();
  if (tid < 128) {
    float pv = sm.r.pv[0][tid]; int pi_ = sm.r.pi[0][tid];
    float nv = sm.r.nv[0][tid]; int ni_ = sm.r.ni[0][tid];
    const float pv1 = sm.r.pv[1][tid]; const int pi1 = sm.r.pi[1][tid];
    const float nv1 = sm.r.nv[1][tid]; const int ni1 = sm.r.ni[1][tid];
    if (pv1 > pv) { pv = pv1; pi_ = pi1; }   // wc=0 has lower cols: ties keep wc0
    if (nv1 < nv) { nv = nv1; ni_ = ni1; }
    const size_t o = (size_t)(i0 + tid) * NCHUNK + jb;
    part_pv[o] = pv; part_pi[o] = pi_;
    part_nv[o] = nv; part_ni[o] = ni_;
  }
}

// ---------------------------------------------------------------------------
// Fused combine + finalize: one wave per anchor. Lanes 0..31 reduce the 32
// positive-chunk partials (argmax), lanes 32..63 the negative ones (argmin,
// via negated key); both maximize (key, -idx) so ties keep the smallest index
// (== reference first-index argmax/argmin semantics, since chunk order is
// index order). Then fp32 recompute of the three distances; store loss[a].
__global__ __launch_bounds__(256)
void finalize_kernel(const float* __restrict__ E, const float* __restrict__ sq,
                     const float* __restrict__ ppv, const int* __restrict__ ppi,
                     const float* __restrict__ pnv, const int* __restrict__ pni,
                     float* __restrict__ loss) {
  const int a = blockIdx.x * 4 + (threadIdx.x >> 6);
  const int lane = threadIdx.x & 63;
  const int ch = lane & 31;
  float key; int idx;
  if (lane < 32) { key = ppv[(size_t)a * NCHUNK + ch]; idx = ppi[(size_t)a * NCHUNK + ch]; }
  else           { key = -pnv[(size_t)a * NCHUNK + ch]; idx = pni[(size_t)a * NCHUNK + ch]; }
#pragma unroll
  for (int off = 1; off < 32; off <<= 1) {   // stays within each 32-lane half
    const float ok = __shfl_xor(key, off); const int oi = __shfl_xor(idx, off);
    if (ok > key || (ok == key && oi < idx)) { key = ok; idx = oi; }
  }
  const int p = __shfl(idx, 0);
  const int n = __shfl(idx, 32);
  const bool valid = (p < NN) && (n < NN);
  const int pp = valid ? p : 0, nn = valid ? n : 0;

  const float4 xa = *(const float4*)&E[(size_t)a * DD + lane * 4];
  const float4 xp = *(const float4*)&E[(size_t)pp * DD + lane * 4];
  const float4 xn = *(const float4*)&E[(size_t)nn * DD + lane * 4];
  float dap = xa.x * xp.x + xa.y * xp.y + xa.z * xp.z + xa.w * xp.w;
  float dan = xa.x * xn.x + xa.y * xn.y + xa.z * xn.z + xa.w * xn.w;
  float dpn = xp.x * xn.x + xp.y * xn.y + xp.z * xn.z + xp.w * xn.w;
#pragma unroll
  for (int off = 32; off > 0; off >>= 1) {
    dap += __shfl_down(dap, off);
    dan += __shfl_down(dan, off);
    dpn += __shfl_down(dpn, off);
  }
  if (lane == 0) {
    float l = 0.f;
    if (valid) {
      const float d2ap = fmaxf(sq[a] + sq[pp] - 2.f * dap, 0.f);
      const float d2an = fmaxf(sq[a] + sq[nn] - 2.f * dan, 0.f);
      const float d2pn = fmaxf(sq[pp] + sq[nn] - 2.f * dpn, 0.f);
      l = fmaxf(sqrtf(d2ap) - fminf(sqrtf(d2an), sqrtf(d2pn)) + MARGIN, 0.f);
    }
    loss[a] = l;
  }
}

// ---------------------------------------------------------------------------
// Single block: sum + nonzero-count over loss[NN], write the scalar output.
__global__ __launch_bounds__(1024)
void reduce_kernel(const float* __restrict__ loss, float* __restrict__ out) {
  __shared__ float s_sum[16], s_cnt[16];
  const int tid = threadIdx.x;
  const float4 v = *(const float4*)&loss[tid * 4];
  float s = v.x + v.y + v.z + v.w;
  float c = (v.x > 0.f) + (v.y > 0.f) + (v.z > 0.f) + (v.w > 0.f);
#pragma unroll
  for (int off = 32; off > 0; off >>= 1) {
    s += __shfl_down(s, off);
    c += __shfl_down(c, off);
  }
  if ((tid & 63) == 0) { s_sum[tid >> 6] = s; s_cnt[tid >> 6] = c; }
  __syncthreads();
  if (tid == 0) {
    float ts = 0.f, tc = 0.f;
#pragma unroll
    for (int w = 0; w < 16; ++w) { ts += s_sum[w]; tc += s_cnt[w]; }
    out[0] = (tc > 0.f) ? (ts / fmaxf(tc, 1.f)) : 0.f;
  }
}

// ---------------------------------------------------------------------------
extern "C" void kernel_launch(void* const* d_in, const int* in_sizes, int n_in,
                              void* d_out, int out_size, void* d_ws, size_t ws_size,
                              hipStream_t stream) {
  const float* E = (const float*)d_in[0];
  const void* posm = d_in[1];
  float* out = (float*)d_out;
  char* ws = (char*)d_ws;

  int* flagbits = (int*)(ws + OFF_FLAG);
  float* sq = (float*)(ws + OFF_SQ);
  f16* Eh = (f16*)(ws + OFF_EH);
  u64* posb = (u64*)(ws + OFF_POSB);
  float* ppv = (float*)(ws + OFF_PPV);
  int* ppi = (int*)(ws + OFF_PPI);
  float* pnv = (float*)(ws + OFF_PNV);
  int* pni = (int*)(ws + OFF_PNI);
  float* loss = (float*)(ws + OFF_LOSS);

  hipMemsetAsync(ws, 0, 64, stream);  // zero flagbits
  detect_kernel<<<64, 256, 0, stream>>>((const unsigned int*)posm, flagbits);
  repack_kernel<<<(int)((long long)NN * NN / 1024), 256, 0, stream>>>(posm, posb, flagbits);
  convert_kernel<<<NN / 4, 256, 0, stream>>>(E, Eh, sq);
  mine_kernel<<<32 * NCHUNK, 256, 0, stream>>>(Eh, sq, posb, ppv, ppi, pnv, pni);
  finalize_kernel<<<NN / 4, 256, 0, stream>>>(E, sq, ppv, ppi, pnv, pni, loss);
  reduce_kernel<<<1, 1024, 0, stream>>>(loss, out);
}